// Round 5
// baseline (1400.414 us; speedup 1.0000x reference)
//
#include <hip/hip_runtime.h>
#include <hip/hip_bf16.h>
#include <hip/hip_fp16.h>

#define N_NODES 50000
#define N_EDGES 800000
#define NTILES 3125        // N_NODES / 16
#define W_TOTAL 57344      // packed bf16 weight elements
#define EB 3125            // edge blocks (N_EDGES/256)
#define WB 224             // weight-pack blocks
#define NB 782             // dst buckets: ceil(50000/64)
#define BCAP 2048          // entries per bucket (mean 1024, sigma 32 -> safe)

typedef __attribute__((ext_vector_type(8))) short bf16x8;   // MFMA A/B frag
typedef __attribute__((ext_vector_type(4))) float f32x4;    // MFMA C/D frag

__device__ inline float bf2f(unsigned short u) {
    return __uint_as_float(((unsigned int)u) << 16);
}
__device__ inline unsigned short f2bf(float f) {  // round-to-nearest-even
    unsigned int x = __float_as_uint(f);
    unsigned int r = (x + 0x7FFF + ((x >> 16) & 1)) >> 16;
    return (unsigned short)r;
}
__device__ inline float2 h2f2(unsigned int u) {   // packed half2 -> float2
    __half2 h = *(__half2*)&u;
    return make_float2(__low2float(h), __high2float(h));
}

// ---------------------------------------------------------------------------
// fused: bucketize edges by dst>>6 (blocks [0,EB)) + weight bf16 pack (rest).
// Bucket entry = (src<<6) | (dst&63), one uint per edge.
__global__ __launch_bounds__(256) void bucketize_pack_kernel(
    const int* __restrict__ src, const int* __restrict__ dst,
    int* __restrict__ bcnt, unsigned int* __restrict__ bkt,
    const float* W1, const float* W2, const float* A2a, const float* A2b,
    const float* W3, const float* A3a, const float* A3b,
    const float* W4, const float* A4a, const float* A4b,
    unsigned short* __restrict__ wp) {
    if (blockIdx.x < EB) {
        int e = blockIdx.x * 256 + threadIdx.x;   // EB*256 == N_EDGES exactly
        int d = dst[e], s = src[e];
        int b = d >> 6;
        int pos = atomicAdd(&bcnt[b], 1);
        if (pos < BCAP)
            bkt[(size_t)b * BCAP + pos] = ((unsigned int)s << 6) | (unsigned int)(d & 63);
    } else {
        int i = (blockIdx.x - EB) * 256 + threadIdx.x;
        if (i >= W_TOTAL) return;
        float v;
        if (i < 8192)       v = W1[i];
        else if (i < 16384) v = W2[i - 8192];
        else if (i < 20480) v = A2a[i - 16384];
        else if (i < 24576) v = A2b[i - 20480];
        else if (i < 32768) v = W3[i - 24576];
        else if (i < 36864) v = A3a[i - 32768];
        else if (i < 40960) v = A3b[i - 36864];
        else if (i < 49152) v = W4[i - 40960];
        else if (i < 53248) v = A4a[i - 49152];
        else                v = A4b[i - 53248];
        wp[i] = f2bf(v);
    }
}

// ---------------------------------------------------------------------------
// per-bucket degree histogram (LDS) -> isq = rsqrt(max(deg,1))
__global__ __launch_bounds__(256) void isq_bucket(const unsigned int* __restrict__ bkt,
                                                  const int* __restrict__ bcnt,
                                                  float* __restrict__ isq) {
    __shared__ int hist[64];
    int tid = threadIdx.x;
    if (tid < 64) hist[tid] = 0;
    __syncthreads();
    int b = blockIdx.x;
    int cnt = min(bcnt[b], BCAP);
    const unsigned int* be = bkt + (size_t)b * BCAP;
    for (int i = tid; i < cnt; i += 256) atomicAdd(&hist[be[i] & 63], 1);
    __syncthreads();
    int d = b * 64 + tid;
    if (tid < 64 && d < N_NODES) isq[d] = rsqrtf(fmaxf((float)hist[tid], 1.0f));
}

// ---------------------------------------------------------------------------
// layer1: h = relu(x @ W1^T + b1) via 16x16x32 bf16 MFMA; epilogue also writes
// hs = isq[row]*h as fp16 (pre-scaled rows for the conv gather).
__global__ __launch_bounds__(256) void layer1_mfma(const float* __restrict__ x,
                                                   const unsigned short* __restrict__ w1p,
                                                   const float* __restrict__ b1,
                                                   const float* __restrict__ isq,
                                                   unsigned short* __restrict__ outh,
                                                   __half* __restrict__ outs) {
    int wave = (blockIdx.x * 256 + threadIdx.x) >> 6;
    if (wave >= NTILES) return;
    int lane = threadIdx.x & 63;
    int r16 = lane & 15, quad = lane >> 4;
    int base = wave * 16;

    bf16x8 a[4];
    const float* xr = x + (size_t)(base + r16) * 128 + quad * 8;
#pragma unroll
    for (int kb = 0; kb < 4; kb++) {
        float4 f0 = *(const float4*)(xr + kb * 32);
        float4 f1 = *(const float4*)(xr + kb * 32 + 4);
        bf16x8 v;
        v[0] = (short)f2bf(f0.x); v[1] = (short)f2bf(f0.y);
        v[2] = (short)f2bf(f0.z); v[3] = (short)f2bf(f0.w);
        v[4] = (short)f2bf(f1.x); v[5] = (short)f2bf(f1.y);
        v[6] = (short)f2bf(f1.z); v[7] = (short)f2bf(f1.w);
        a[kb] = v;
    }

    float isq4[4];
#pragma unroll
    for (int r = 0; r < 4; r++) isq4[r] = isq[base + quad * 4 + r];

#pragma unroll
    for (int jt = 0; jt < 4; jt++) {
        f32x4 acc = {0.f, 0.f, 0.f, 0.f};
        const unsigned short* wr = w1p + (size_t)(jt * 16 + r16) * 128 + quad * 8;
#pragma unroll
        for (int kb = 0; kb < 4; kb++) {
            bf16x8 b = *(const bf16x8*)(wr + kb * 32);
            acc = __builtin_amdgcn_mfma_f32_16x16x32_bf16(a[kb], b, acc, 0, 0, 0);
        }
        int col = jt * 16 + r16;
        float bias = b1[col];
#pragma unroll
        for (int r = 0; r < 4; r++) {
            int row = base + quad * 4 + r;
            float v = fmaxf(acc[r] + bias, 0.f);
            outh[(size_t)row * 64 + col] = f2bf(v);
            outs[(size_t)row * 64 + col] = __float2half(v * isq4[r]);
        }
    }
}

// ---------------------------------------------------------------------------
// conv: one workgroup per 64-dst bucket; LDS fp32 accumulator in even/odd
// feature planes (lane l -> bank l: conflict-free ds_add_f32). Each half-wave
// handles one edge: 32 lanes x 4B = full 128B hs row gather.
__global__ __launch_bounds__(512) void conv_bucket(const __half* __restrict__ hs,
                                                   const unsigned int* __restrict__ bkt,
                                                   const int* __restrict__ bcnt,
                                                   const float* __restrict__ isq,
                                                   unsigned short* __restrict__ out) {
    __shared__ float accX[64][32];   // feats 0,2,4,..,62
    __shared__ float accY[64][32];   // feats 1,3,5,..,63
    int tid = threadIdx.x;
#pragma unroll
    for (int k = 0; k < 4; k++) {
        (&accX[0][0])[tid + k * 512] = 0.f;
        (&accY[0][0])[tid + k * 512] = 0.f;
    }
    __syncthreads();

    int b = blockIdx.x;
    int cnt = min(bcnt[b], BCAP);
    const unsigned int* be = bkt + (size_t)b * BCAP;
    const unsigned int* hsp = (const unsigned int*)hs;   // hs row = 32 uints
    int wid = tid >> 6;            // 0..7
    int lane = tid & 63;
    int half = lane >> 5;          // half-wave id
    int l = lane & 31;             // feat pair: 2l, 2l+1

    int i = wid * 2 + half;
    for (; i + 16 < cnt; i += 32) {         // 2 independent chains in flight
        unsigned int p0 = be[i];
        unsigned int p1 = be[i + 16];
        float2 f0 = h2f2(hsp[(size_t)(p0 >> 6) * 32 + l]);
        float2 f1 = h2f2(hsp[(size_t)(p1 >> 6) * 32 + l]);
        atomicAdd(&accX[p0 & 63][l], f0.x);
        atomicAdd(&accY[p0 & 63][l], f0.y);
        atomicAdd(&accX[p1 & 63][l], f1.x);
        atomicAdd(&accY[p1 & 63][l], f1.y);
    }
    for (; i < cnt; i += 16) {
        unsigned int p = be[i];
        float2 f = h2f2(hsp[(size_t)(p >> 6) * 32 + l]);
        atomicAdd(&accX[p & 63][l], f.x);
        atomicAdd(&accY[p & 63][l], f.y);
    }
    __syncthreads();

    int base = b * 64;
    for (int row = wid; row < 64; row += 8) {
        int d = base + row;
        if (d >= N_NODES) break;
        float v = (lane & 1) ? accY[row][lane >> 1] : accX[row][lane >> 1];
        out[(size_t)d * 64 + lane] = f2bf(v * isq[d]);
    }
}

// ---------------------------------------------------------------------------
// dense block: out = relu( [h,conv]@W^T + (h@Aa^T)*(h@Ab^T) )
// epilogue writes h (bf16) + hs = isq*h (fp16) unless final layer (fp32 out).
__global__ __launch_bounds__(256) void dense_mfma(const unsigned short* __restrict__ h,
                                                  const unsigned short* __restrict__ cv,
                                                  const unsigned short* __restrict__ wp,
                                                  const unsigned short* __restrict__ aap,
                                                  const unsigned short* __restrict__ abp,
                                                  const float* __restrict__ isq,
                                                  unsigned short* __restrict__ outh,
                                                  __half* __restrict__ outs,
                                                  float* __restrict__ outf,
                                                  int finalLayer) {
    int wave = (blockIdx.x * 256 + threadIdx.x) >> 6;
    if (wave >= NTILES) return;
    int lane = threadIdx.x & 63;
    int r16 = lane & 15, quad = lane >> 4;
    int base = wave * 16;

    const unsigned short* hr = h + (size_t)(base + r16) * 64 + quad * 8;
    const unsigned short* cr = cv + (size_t)(base + r16) * 64 + quad * 8;
    bf16x8 ha0 = *(const bf16x8*)(hr);
    bf16x8 ha1 = *(const bf16x8*)(hr + 32);
    bf16x8 ca0 = *(const bf16x8*)(cr);
    bf16x8 ca1 = *(const bf16x8*)(cr + 32);

    float isq4[4];
    if (!finalLayer) {
#pragma unroll
        for (int r = 0; r < 4; r++) isq4[r] = isq[base + quad * 4 + r];
    }

#pragma unroll
    for (int jt = 0; jt < 4; jt++) {
        const unsigned short* wr = wp + (size_t)(jt * 16 + r16) * 128 + quad * 8;
        const unsigned short* ar = aap + (size_t)(jt * 16 + r16) * 64 + quad * 8;
        const unsigned short* br = abp + (size_t)(jt * 16 + r16) * 64 + quad * 8;
        f32x4 P = {0.f, 0.f, 0.f, 0.f};
        f32x4 Q = {0.f, 0.f, 0.f, 0.f};
        f32x4 R = {0.f, 0.f, 0.f, 0.f};
        P = __builtin_amdgcn_mfma_f32_16x16x32_bf16(ha0, *(const bf16x8*)(wr), P, 0, 0, 0);
        P = __builtin_amdgcn_mfma_f32_16x16x32_bf16(ha1, *(const bf16x8*)(wr + 32), P, 0, 0, 0);
        P = __builtin_amdgcn_mfma_f32_16x16x32_bf16(ca0, *(const bf16x8*)(wr + 64), P, 0, 0, 0);
        P = __builtin_amdgcn_mfma_f32_16x16x32_bf16(ca1, *(const bf16x8*)(wr + 96), P, 0, 0, 0);
        Q = __builtin_amdgcn_mfma_f32_16x16x32_bf16(ha0, *(const bf16x8*)(ar), Q, 0, 0, 0);
        Q = __builtin_amdgcn_mfma_f32_16x16x32_bf16(ha1, *(const bf16x8*)(ar + 32), Q, 0, 0, 0);
        R = __builtin_amdgcn_mfma_f32_16x16x32_bf16(ha0, *(const bf16x8*)(br), R, 0, 0, 0);
        R = __builtin_amdgcn_mfma_f32_16x16x32_bf16(ha1, *(const bf16x8*)(br + 32), R, 0, 0, 0);
        int col = jt * 16 + r16;
#pragma unroll
        for (int r = 0; r < 4; r++) {
            int row = base + quad * 4 + r;
            float v = fmaxf(P[r] + Q[r] * R[r], 0.f);
            if (finalLayer) {
                outf[(size_t)row * 64 + col] = v;
            } else {
                outh[(size_t)row * 64 + col] = f2bf(v);
                outs[(size_t)row * 64 + col] = __float2half(v * isq4[r]);
            }
        }
    }
}

// ---------------------------------------------------------------------------
extern "C" void kernel_launch(void* const* d_in, const int* in_sizes, int n_in,
                              void* d_out, int out_size, void* d_ws, size_t ws_size,
                              hipStream_t stream) {
    const float* x = (const float*)d_in[0];
    const int* edges = (const int*)d_in[1];
    const float* W1 = (const float*)d_in[2];
    const float* b1 = (const float*)d_in[3];
    const float* W2 = (const float*)d_in[4];
    const float* A2a = (const float*)d_in[5];
    const float* A2b = (const float*)d_in[6];
    const float* W3 = (const float*)d_in[7];
    const float* A3a = (const float*)d_in[8];
    const float* A3b = (const float*)d_in[9];
    const float* W4 = (const float*)d_in[10];
    const float* A4a = (const float*)d_in[11];
    const float* A4b = (const float*)d_in[12];
    float* out = (float*)d_out;

    const int* src = edges;
    const int* dst = edges + N_EDGES;

    char* p = (char*)d_ws;
    auto alloc = [&](size_t bytes) {
        char* r = p;
        p += (bytes + 255) & ~(size_t)255;
        return r;
    };
    int* bcnt             = (int*)alloc(NB * 4);
    unsigned int* bkt     = (unsigned int*)alloc((size_t)NB * BCAP * 4);
    float* isq            = (float*)alloc(N_NODES * 4);
    unsigned short* wpAll = (unsigned short*)alloc(W_TOTAL * 2);
    unsigned short* Ah    = (unsigned short*)alloc((size_t)N_NODES * 64 * 2);
    __half* As            = (__half*)alloc((size_t)N_NODES * 64 * 2);
    unsigned short* Bh    = (unsigned short*)alloc((size_t)N_NODES * 64 * 2);
    unsigned short* C     = (unsigned short*)alloc((size_t)N_NODES * 64 * 2);

    const unsigned short* W1p  = wpAll;
    const unsigned short* W2p  = wpAll + 8192;
    const unsigned short* A2ap = wpAll + 16384;
    const unsigned short* A2bp = wpAll + 20480;
    const unsigned short* W3p  = wpAll + 24576;
    const unsigned short* A3ap = wpAll + 32768;
    const unsigned short* A3bp = wpAll + 36864;
    const unsigned short* W4p  = wpAll + 40960;
    const unsigned short* A4ap = wpAll + 49152;
    const unsigned short* A4bp = wpAll + 53248;

    const int TB = (NTILES + 3) / 4;          // dense/layer1 blocks (4 waves ea.)

    // ---- bucket build + weight pack ----
    hipMemsetAsync(bcnt, 0, NB * 4, stream);
    bucketize_pack_kernel<<<EB + WB, 256, 0, stream>>>(src, dst, bcnt, bkt, W1, W2, A2a,
                                                       A2b, W3, A3a, A3b, W4, A4a, A4b,
                                                       wpAll);
    isq_bucket<<<NB, 256, 0, stream>>>(bkt, bcnt, isq);

    // ---- layer 1: x -> Ah (bf16) + As (fp16, pre-scaled) ----
    layer1_mfma<<<TB, 256, 0, stream>>>(x, W1p, b1, isq, Ah, As);

    // ---- block 2 ----
    conv_bucket<<<NB, 512, 0, stream>>>(As, bkt, bcnt, isq, C);
    dense_mfma<<<TB, 256, 0, stream>>>(Ah, C, W2p, A2ap, A2bp, isq, Bh, As, nullptr, 0);

    // ---- block 3 ----
    conv_bucket<<<NB, 512, 0, stream>>>(As, bkt, bcnt, isq, C);
    dense_mfma<<<TB, 256, 0, stream>>>(Bh, C, W3p, A3ap, A3bp, isq, Ah, As, nullptr, 0);

    // ---- block 4 -> d_out (fp32) ----
    conv_bucket<<<NB, 512, 0, stream>>>(As, bkt, bcnt, isq, C);
    dense_mfma<<<TB, 256, 0, stream>>>(Ah, C, W4p, A4ap, A4bp, isq, nullptr, nullptr, out, 1);
}

// Round 6
// 300.681 us; speedup vs baseline: 4.6575x; 4.6575x over previous
//
#include <hip/hip_runtime.h>
#include <hip/hip_bf16.h>
#include <hip/hip_fp16.h>

#define N_NODES 50000
#define N_EDGES 800000
#define NTILES 3125        // N_NODES / 16
#define SCAN_NB 196        // ceil(N_NODES / 256)
#define W_TOTAL 57344      // packed bf16 weight elements
#define WB 224             // weight-pack blocks
#define SRC_PAD 512        // sentinel tail on srcA
#define CLS_BLOCKS 1024    // classed edge-walk blocks (128 per XCD class)
#define CLS_STRIDE (128 * 256)
#define CLS_RANGE 6250     // dst nodes per class (8 * 6250 = 50000)
#define TB 782             // layer1/dense MFMA blocks (4 waves each)

typedef __attribute__((ext_vector_type(8))) short bf16x8;   // MFMA A/B frag
typedef __attribute__((ext_vector_type(4))) float f32x4;    // MFMA C/D frag

__device__ inline float bf2f(unsigned short u) {
    return __uint_as_float(((unsigned int)u) << 16);
}
__device__ inline unsigned short f2bf(float f) {  // round-to-nearest-even
    unsigned int x = __float_as_uint(f);
    unsigned int r = (x + 0x7FFF + ((x >> 16) & 1)) >> 16;
    return (unsigned short)r;
}
__device__ inline float2 h2f2(unsigned int u) {   // packed half2 -> float2
    __half2 h = *(__half2*)&u;
    return make_float2(__low2float(h), __high2float(h));
}

// ---------------------------------------------------------------------------
// fused: XCD-classed degree count (blocks [0,CLS_BLOCKS)) + weight pack (rest).
// Class c (= blockIdx&7, pinned to one XCD by round-robin dispatch) counts only
// dsts in [c*6250,(c+1)*6250) -> degi atomics + target lines stay in that XCD's L2.
__global__ __launch_bounds__(256) void count_pack_kernel(
    const int* __restrict__ dst, int* __restrict__ degi,
    const float* W1, const float* W2, const float* A2a, const float* A2b,
    const float* W3, const float* A3a, const float* A3b,
    const float* W4, const float* A4a, const float* A4b,
    unsigned short* __restrict__ wp) {
    if (blockIdx.x < CLS_BLOCKS) {
        int cls = blockIdx.x & 7;
        int k = blockIdx.x >> 3;
        int lo = cls * CLS_RANGE, hi = lo + CLS_RANGE;
        for (int e = k * 256 + (int)threadIdx.x; e < N_EDGES; e += CLS_STRIDE) {
            int d = dst[e];
            if (d >= lo && d < hi) atomicAdd(&degi[d], 1);
        }
    } else {
        int i = (blockIdx.x - CLS_BLOCKS) * 256 + threadIdx.x;
        if (i >= W_TOTAL) return;
        float v;
        if (i < 8192)       v = W1[i];
        else if (i < 16384) v = W2[i - 8192];
        else if (i < 20480) v = A2a[i - 16384];
        else if (i < 24576) v = A2b[i - 20480];
        else if (i < 32768) v = W3[i - 24576];
        else if (i < 36864) v = A3a[i - 32768];
        else if (i < 40960) v = A3b[i - 36864];
        else if (i < 49152) v = W4[i - 40960];
        else if (i < 53248) v = A4a[i - 49152];
        else                v = A4b[i - 53248];
        wp[i] = f2bf(v);
    }
}

// scan phase 1: per-256-chunk inclusive scan + chunk totals; also isq = rsqrt(max(deg,1))
__global__ __launch_bounds__(256) void scan1_kernel(const int* __restrict__ degi,
                                                    int* __restrict__ incl,
                                                    int* __restrict__ partial,
                                                    float* __restrict__ isq) {
    __shared__ int s[256];
    int gid = blockIdx.x * 256 + threadIdx.x;
    int v = (gid < N_NODES) ? degi[gid] : 0;
    if (gid < N_NODES) isq[gid] = rsqrtf(fmaxf((float)v, 1.0f));
    s[threadIdx.x] = v;
    __syncthreads();
    for (int off = 1; off < 256; off <<= 1) {
        int t = (threadIdx.x >= off) ? s[threadIdx.x - off] : 0;
        __syncthreads();
        s[threadIdx.x] += t;
        __syncthreads();
    }
    if (gid < N_NODES) incl[gid] = s[threadIdx.x];
    if (threadIdx.x == 255) partial[blockIdx.x] = s[255];
}

// scan phase 2 (one block): exclusive scan of chunk totals + srcA sentinel init
__global__ __launch_bounds__(256) void scan2_kernel(int* __restrict__ partial,
                                                    int* __restrict__ srcA) {
    __shared__ int s[256];
    int v = (threadIdx.x < SCAN_NB) ? partial[threadIdx.x] : 0;
    s[threadIdx.x] = v;
    __syncthreads();
    for (int off = 1; off < 256; off <<= 1) {
        int t = (threadIdx.x >= off) ? s[threadIdx.x - off] : 0;
        __syncthreads();
        s[threadIdx.x] += t;
        __syncthreads();
    }
    if (threadIdx.x < SCAN_NB) partial[threadIdx.x] = s[threadIdx.x] - v;  // exclusive
    srcA[N_EDGES + threadIdx.x] = 0;            // sentinel tail (node 0)
    srcA[N_EDGES + 256 + threadIdx.x] = 0;
}

// scan phase 3: rowptr (exclusive) + cursor copy
__global__ __launch_bounds__(256) void scan3_kernel(const int* __restrict__ incl,
                                                    const int* __restrict__ partial,
                                                    const int* __restrict__ degi,
                                                    int* __restrict__ rowptr,
                                                    int* __restrict__ cursor) {
    int gid = blockIdx.x * 256 + threadIdx.x;
    if (gid < N_NODES) {
        int excl = partial[blockIdx.x] + incl[gid] - degi[gid];
        rowptr[gid] = excl;
        cursor[gid] = excl;
    }
    if (gid == 0) rowptr[N_NODES] = N_EDGES;
}

// ---------------------------------------------------------------------------
// fused layer1 + classed scatter.
// blocks [0,TB): h = relu(x @ W1^T + b1) via MFMA; epilogue writes h (bf16) and
//   hs = isq*h (fp16).
// blocks [TB,TB+CLS_BLOCKS): CSR scatter, class-filtered by dst range so each
//   class's srcA window (~400KB) and cursors stay in one XCD's L2.
__global__ __launch_bounds__(256) void layer1_scatter(const float* __restrict__ x,
                                                      const unsigned short* __restrict__ w1p,
                                                      const float* __restrict__ b1,
                                                      const float* __restrict__ isq,
                                                      unsigned short* __restrict__ outh,
                                                      __half* __restrict__ outs,
                                                      const int* __restrict__ src,
                                                      const int* __restrict__ dst,
                                                      int* __restrict__ cursor,
                                                      int* __restrict__ srcA) {
    if (blockIdx.x >= TB) {
        int cb = blockIdx.x - TB;
        int cls = cb & 7;
        int k = cb >> 3;
        int lo = cls * CLS_RANGE, hi = lo + CLS_RANGE;
        for (int e = k * 256 + (int)threadIdx.x; e < N_EDGES; e += CLS_STRIDE) {
            int d = dst[e];
            if (d >= lo && d < hi) {
                int pos = atomicAdd(&cursor[d], 1);
                srcA[pos] = src[e];
            }
        }
        return;
    }

    int wave = (blockIdx.x * 256 + threadIdx.x) >> 6;
    if (wave >= NTILES) return;
    int lane = threadIdx.x & 63;
    int r16 = lane & 15, quad = lane >> 4;
    int base = wave * 16;

    bf16x8 a[4];
    const float* xr = x + (size_t)(base + r16) * 128 + quad * 8;
#pragma unroll
    for (int kb = 0; kb < 4; kb++) {
        float4 f0 = *(const float4*)(xr + kb * 32);
        float4 f1 = *(const float4*)(xr + kb * 32 + 4);
        bf16x8 v;
        v[0] = (short)f2bf(f0.x); v[1] = (short)f2bf(f0.y);
        v[2] = (short)f2bf(f0.z); v[3] = (short)f2bf(f0.w);
        v[4] = (short)f2bf(f1.x); v[5] = (short)f2bf(f1.y);
        v[6] = (short)f2bf(f1.z); v[7] = (short)f2bf(f1.w);
        a[kb] = v;
    }

    float isq4[4];
#pragma unroll
    for (int r = 0; r < 4; r++) isq4[r] = isq[base + quad * 4 + r];

#pragma unroll
    for (int jt = 0; jt < 4; jt++) {
        f32x4 acc = {0.f, 0.f, 0.f, 0.f};
        const unsigned short* wr = w1p + (size_t)(jt * 16 + r16) * 128 + quad * 8;
#pragma unroll
        for (int kb = 0; kb < 4; kb++) {
            bf16x8 b = *(const bf16x8*)(wr + kb * 32);
            acc = __builtin_amdgcn_mfma_f32_16x16x32_bf16(a[kb], b, acc, 0, 0, 0);
        }
        int col = jt * 16 + r16;
        float bias = b1[col];
#pragma unroll
        for (int r = 0; r < 4; r++) {
            int row = base + quad * 4 + r;
            float v = fmaxf(acc[r] + bias, 0.f);
            outh[(size_t)row * 64 + col] = f2bf(v);
            outs[(size_t)row * 64 + col] = __float2half(v * isq4[r]);
        }
    }
}

// ---------------------------------------------------------------------------
// conv (CSR, 4 rows/wave): out[d,:] = isq[d] * sum_{e in row d} hs[src_e,:]
// quarter-wave per dst row; lane covers 4 feats (ushort4 = one 8B gather);
// one gather instruction serves 4 edges. Sentinel-padded srcA keeps all loads
// unconditional; accumulate is masked.
__global__ __launch_bounds__(256) void conv_csr4(const __half* __restrict__ hs,
                                                 const int* __restrict__ rowptr,
                                                 const int* __restrict__ srcA,
                                                 const float* __restrict__ isq,
                                                 unsigned short* __restrict__ out) {
    int wave = (blockIdx.x * 256 + threadIdx.x) >> 6;
    if (wave >= N_NODES / 4) return;
    int lane = threadIdx.x & 63;
    int q = lane >> 4, fl = lane & 15;
    int d = wave * 4 + q;
    int b = rowptr[d];
    int cnt = rowptr[d + 1] - b;
    int m = cnt;
    m = max(m, __shfl_xor(m, 16));
    m = max(m, __shfl_xor(m, 32));

    const unsigned int* hsp = (const unsigned int*)hs;  // 1 uint = 2 halves
    float a0 = 0.f, a1 = 0.f, a2 = 0.f, a3 = 0.f;
    for (int i = 0; i < m; i += 4) {
#pragma unroll
        for (int u = 0; u < 4; u++) {
            int j = i + u;
            int s = srcA[b + j];                       // sentinel-safe
            uint2 raw = *(const uint2*)(hsp + ((size_t)s << 5) + (fl << 1));
            bool ok = j < cnt;
            unsigned int r0 = ok ? raw.x : 0u;
            unsigned int r1 = ok ? raw.y : 0u;
            float2 f0 = h2f2(r0), f1 = h2f2(r1);
            a0 += f0.x; a1 += f0.y; a2 += f1.x; a3 += f1.y;
        }
    }
    float sc = isq[d];
    ushort4 o;
    o.x = f2bf(a0 * sc); o.y = f2bf(a1 * sc);
    o.z = f2bf(a2 * sc); o.w = f2bf(a3 * sc);
    *(ushort4*)(out + (size_t)d * 64 + fl * 4) = o;
}

// ---------------------------------------------------------------------------
// dense block: out = relu( [h,conv]@W^T + (h@Aa^T)*(h@Ab^T) )
// epilogue writes h (bf16) + hs = isq*h (fp16) unless final layer (fp32 out).
__global__ __launch_bounds__(256) void dense_mfma(const unsigned short* __restrict__ h,
                                                  const unsigned short* __restrict__ cv,
                                                  const unsigned short* __restrict__ wp,
                                                  const unsigned short* __restrict__ aap,
                                                  const unsigned short* __restrict__ abp,
                                                  const float* __restrict__ isq,
                                                  unsigned short* __restrict__ outh,
                                                  __half* __restrict__ outs,
                                                  float* __restrict__ outf,
                                                  int finalLayer) {
    int wave = (blockIdx.x * 256 + threadIdx.x) >> 6;
    if (wave >= NTILES) return;
    int lane = threadIdx.x & 63;
    int r16 = lane & 15, quad = lane >> 4;
    int base = wave * 16;

    const unsigned short* hr = h + (size_t)(base + r16) * 64 + quad * 8;
    const unsigned short* cr = cv + (size_t)(base + r16) * 64 + quad * 8;
    bf16x8 ha0 = *(const bf16x8*)(hr);
    bf16x8 ha1 = *(const bf16x8*)(hr + 32);
    bf16x8 ca0 = *(const bf16x8*)(cr);
    bf16x8 ca1 = *(const bf16x8*)(cr + 32);

    float isq4[4];
    if (!finalLayer) {
#pragma unroll
        for (int r = 0; r < 4; r++) isq4[r] = isq[base + quad * 4 + r];
    }

#pragma unroll
    for (int jt = 0; jt < 4; jt++) {
        const unsigned short* wr = wp + (size_t)(jt * 16 + r16) * 128 + quad * 8;
        const unsigned short* ar = aap + (size_t)(jt * 16 + r16) * 64 + quad * 8;
        const unsigned short* br = abp + (size_t)(jt * 16 + r16) * 64 + quad * 8;
        f32x4 P = {0.f, 0.f, 0.f, 0.f};
        f32x4 Q = {0.f, 0.f, 0.f, 0.f};
        f32x4 R = {0.f, 0.f, 0.f, 0.f};
        P = __builtin_amdgcn_mfma_f32_16x16x32_bf16(ha0, *(const bf16x8*)(wr), P, 0, 0, 0);
        P = __builtin_amdgcn_mfma_f32_16x16x32_bf16(ha1, *(const bf16x8*)(wr + 32), P, 0, 0, 0);
        P = __builtin_amdgcn_mfma_f32_16x16x32_bf16(ca0, *(const bf16x8*)(wr + 64), P, 0, 0, 0);
        P = __builtin_amdgcn_mfma_f32_16x16x32_bf16(ca1, *(const bf16x8*)(wr + 96), P, 0, 0, 0);
        Q = __builtin_amdgcn_mfma_f32_16x16x32_bf16(ha0, *(const bf16x8*)(ar), Q, 0, 0, 0);
        Q = __builtin_amdgcn_mfma_f32_16x16x32_bf16(ha1, *(const bf16x8*)(ar + 32), Q, 0, 0, 0);
        R = __builtin_amdgcn_mfma_f32_16x16x32_bf16(ha0, *(const bf16x8*)(br), R, 0, 0, 0);
        R = __builtin_amdgcn_mfma_f32_16x16x32_bf16(ha1, *(const bf16x8*)(br + 32), R, 0, 0, 0);
        int col = jt * 16 + r16;
#pragma unroll
        for (int r = 0; r < 4; r++) {
            int row = base + quad * 4 + r;
            float v = fmaxf(P[r] + Q[r] * R[r], 0.f);
            if (finalLayer) {
                outf[(size_t)row * 64 + col] = v;
            } else {
                outh[(size_t)row * 64 + col] = f2bf(v);
                outs[(size_t)row * 64 + col] = __float2half(v * isq4[r]);
            }
        }
    }
}

// ---------------------------------------------------------------------------
extern "C" void kernel_launch(void* const* d_in, const int* in_sizes, int n_in,
                              void* d_out, int out_size, void* d_ws, size_t ws_size,
                              hipStream_t stream) {
    const float* x = (const float*)d_in[0];
    const int* edges = (const int*)d_in[1];
    const float* W1 = (const float*)d_in[2];
    const float* b1 = (const float*)d_in[3];
    const float* W2 = (const float*)d_in[4];
    const float* A2a = (const float*)d_in[5];
    const float* A2b = (const float*)d_in[6];
    const float* W3 = (const float*)d_in[7];
    const float* A3a = (const float*)d_in[8];
    const float* A3b = (const float*)d_in[9];
    const float* W4 = (const float*)d_in[10];
    const float* A4a = (const float*)d_in[11];
    const float* A4b = (const float*)d_in[12];
    float* out = (float*)d_out;

    const int* src = edges;
    const int* dst = edges + N_EDGES;

    char* p = (char*)d_ws;
    auto alloc = [&](size_t bytes) {
        char* r = p;
        p += (bytes + 255) & ~(size_t)255;
        return r;
    };
    int* degi             = (int*)alloc(N_NODES * 4);
    int* incl             = (int*)alloc(N_NODES * 4);
    int* partial          = (int*)alloc(256 * 4);
    float* isq            = (float*)alloc(N_NODES * 4);
    int* rowptr           = (int*)alloc((N_NODES + 1) * 4);
    int* cursor           = (int*)alloc(N_NODES * 4);
    int* srcA             = (int*)alloc((N_EDGES + SRC_PAD) * 4);
    unsigned short* wpAll = (unsigned short*)alloc(W_TOTAL * 2);
    unsigned short* Ah    = (unsigned short*)alloc((size_t)N_NODES * 64 * 2);
    __half* As            = (__half*)alloc((size_t)N_NODES * 64 * 2);
    unsigned short* Bh    = (unsigned short*)alloc((size_t)N_NODES * 64 * 2);
    unsigned short* C     = (unsigned short*)alloc((size_t)N_NODES * 64 * 2);

    const unsigned short* W1p  = wpAll;
    const unsigned short* W2p  = wpAll + 8192;
    const unsigned short* A2ap = wpAll + 16384;
    const unsigned short* A2bp = wpAll + 20480;
    const unsigned short* W3p  = wpAll + 24576;
    const unsigned short* A3ap = wpAll + 32768;
    const unsigned short* A3bp = wpAll + 36864;
    const unsigned short* W4p  = wpAll + 40960;
    const unsigned short* A4ap = wpAll + 49152;
    const unsigned short* A4bp = wpAll + 53248;

    const int CB = N_NODES / 4 / 4;           // conv blocks: 12500 waves / 4

    // ---- CSR build + weight pack ----
    hipMemsetAsync(degi, 0, N_NODES * 4, stream);
    count_pack_kernel<<<CLS_BLOCKS + WB, 256, 0, stream>>>(dst, degi, W1, W2, A2a, A2b,
                                                           W3, A3a, A3b, W4, A4a, A4b,
                                                           wpAll);
    scan1_kernel<<<SCAN_NB, 256, 0, stream>>>(degi, incl, partial, isq);
    scan2_kernel<<<1, 256, 0, stream>>>(partial, srcA);
    scan3_kernel<<<SCAN_NB, 256, 0, stream>>>(incl, partial, degi, rowptr, cursor);

    // ---- layer 1 (MFMA) + classed scatter, fused ----
    layer1_scatter<<<TB + CLS_BLOCKS, 256, 0, stream>>>(x, W1p, b1, isq, Ah, As,
                                                        src, dst, cursor, srcA);

    // ---- block 2 ----
    conv_csr4<<<CB, 256, 0, stream>>>(As, rowptr, srcA, isq, C);
    dense_mfma<<<TB, 256, 0, stream>>>(Ah, C, W2p, A2ap, A2bp, isq, Bh, As, nullptr, 0);

    // ---- block 3 ----
    conv_csr4<<<CB, 256, 0, stream>>>(As, rowptr, srcA, isq, C);
    dense_mfma<<<TB, 256, 0, stream>>>(Bh, C, W3p, A3ap, A3bp, isq, Ah, As, nullptr, 0);

    // ---- block 4 -> d_out (fp32) ----
    conv_csr4<<<CB, 256, 0, stream>>>(As, rowptr, srcA, isq, C);
    dense_mfma<<<TB, 256, 0, stream>>>(Ah, C, W4p, A4ap, A4bp, isq, nullptr, nullptr, out, 1);
}